// Round 1
// baseline (440.694 us; speedup 1.0000x reference)
//
#include <hip/hip_runtime.h>
#include <math.h>

// SupCon loss, N=8192 D=128 fp32 in, scalar fp32 out.
// loss = -mean_i [ (sum_{j!=i, lbl_j==lbl_i} sim_ij) - cnt_i*log(sum_{j!=i} exp(sim_ij)+1e-9) ] / max(cnt_i,1)
// sim_ij = dot(norm(f_i), norm(f_j)) / 0.1

constexpr int N = 8192;
constexpr int D = 128;
constexpr int BM = 64;
constexpr int BN = 64;
constexpr float INV_TEMP = 10.0f;

// ---------------- prep: row inverse norms + zero accumulators ----------------
__global__ void prep_kernel(const float* __restrict__ F,
                            float* __restrict__ rnorm,
                            float* __restrict__ rowExp,
                            float* __restrict__ rowPos,
                            float* __restrict__ rowCnt) {
    int row = blockIdx.x;
    int lane = threadIdx.x;  // 64 threads = 1 wave
    const float2* fr = (const float2*)(F + (size_t)row * D);
    float2 v = fr[lane];
    float ss = v.x * v.x + v.y * v.y;
#pragma unroll
    for (int off = 32; off > 0; off >>= 1) ss += __shfl_xor(ss, off);
    if (lane == 0) {
        rnorm[row]  = 1.0f / sqrtf(ss);
        rowExp[row] = 0.0f;   // ws is poisoned 0xAA each launch -> must zero
        rowPos[row] = 0.0f;
        rowCnt[row] = 0.0f;
    }
}

// ---------------- fused sim + exp + masked accumulation ----------------
// Grid (N/BN, N/BM); 256 threads; each thread owns a 4x4 sub-tile.
// LDS layout: k-major At[k][r] so compute-side float4 reads are conflict-free.
// Row index XOR-swizzled by ((k>>2)&7)<<2 so the transpose *writes* during
// staging are only 4-way conflicted (1.58x, m136) instead of 32-way (11x).
__global__ __launch_bounds__(256) void sim_kernel(
    const float* __restrict__ F, const int* __restrict__ labels,
    const float* __restrict__ rnorm,
    float* __restrict__ rowExp, float* __restrict__ rowPos,
    float* __restrict__ rowCnt) {
    __shared__ float At[D * BM];  // 32 KB
    __shared__ float Bt[D * BN];  // 32 KB  (total 64 KB -> 2 blocks/CU)

    const int ti = blockIdx.y, tj = blockIdx.x;
    const int i0 = ti * BM, j0 = tj * BN;
    const int t = threadIdx.x;

    // stage both tiles: 2048 float4 per tile / 256 threads = 8 iters
#pragma unroll
    for (int it = 0; it < 8; ++it) {
        int idx = t + it * 256;     // 0..2047
        int r   = idx >> 5;         // tile row (32 float4 per row of 128)
        int kq  = idx & 31;         // float4 index along k
        int sw  = (kq & 7) << 2;
        int rw  = r ^ sw;           // swizzled row slot
        float4 va = ((const float4*)(F + (size_t)(i0 + r) * D))[kq];
        float  sa = rnorm[i0 + r];
        At[(kq * 4 + 0) * BM + rw] = va.x * sa;
        At[(kq * 4 + 1) * BM + rw] = va.y * sa;
        At[(kq * 4 + 2) * BM + rw] = va.z * sa;
        At[(kq * 4 + 3) * BM + rw] = va.w * sa;
        float4 vb = ((const float4*)(F + (size_t)(j0 + r) * D))[kq];
        float  sb = rnorm[j0 + r];
        Bt[(kq * 4 + 0) * BN + rw] = vb.x * sb;
        Bt[(kq * 4 + 1) * BN + rw] = vb.y * sb;
        Bt[(kq * 4 + 2) * BN + rw] = vb.z * sb;
        Bt[(kq * 4 + 3) * BN + rw] = vb.w * sb;
    }
    __syncthreads();

    const int tx = t & 15, ty = t >> 4;
    float acc[4][4] = {};

#pragma unroll 2
    for (int kq = 0; kq < 32; ++kq) {
        int sw = (kq & 7) << 2;
        const float* Ab = &At[(kq * 4) * BM + ((ty * 4) ^ sw)];
        const float* Bb = &Bt[(kq * 4) * BN + ((tx * 4) ^ sw)];
#pragma unroll
        for (int m = 0; m < 4; ++m) {
            float4 a = *(const float4*)(Ab + m * BM);
            float4 b = *(const float4*)(Bb + m * BN);
            float ar[4] = {a.x, a.y, a.z, a.w};
            float br[4] = {b.x, b.y, b.z, b.w};
#pragma unroll
            for (int e = 0; e < 4; ++e)
#pragma unroll
                for (int f = 0; f < 4; ++f)
                    acc[e][f] = fmaf(ar[e], br[f], acc[e][f]);
        }
    }

    // epilogue: exp + masking, per-thread row partials
    int li[4], lj[4];
#pragma unroll
    for (int e = 0; e < 4; ++e) li[e] = labels[i0 + ty * 4 + e];
#pragma unroll
    for (int f = 0; f < 4; ++f) lj[f] = labels[j0 + tx * 4 + f];

    float re[4] = {}, rp[4] = {}, rc[4] = {};
#pragma unroll
    for (int e = 0; e < 4; ++e) {
        int gi = i0 + ty * 4 + e;
#pragma unroll
        for (int f = 0; f < 4; ++f) {
            int gj = j0 + tx * 4 + f;
            float s = acc[e][f] * INV_TEMP;
            if (gi != gj) {
                re[e] += __expf(s);
                if (li[e] == lj[f]) { rp[e] += s; rc[e] += 1.0f; }
            }
        }
    }

    // reduce across the 16 tx lanes (same wave: xor masks 1,2,4,8)
#pragma unroll
    for (int off = 1; off < 16; off <<= 1) {
#pragma unroll
        for (int e = 0; e < 4; ++e) {
            re[e] += __shfl_xor(re[e], off);
            rp[e] += __shfl_xor(rp[e], off);
            rc[e] += __shfl_xor(rc[e], off);
        }
    }
    if (tx == 0) {
#pragma unroll
        for (int e = 0; e < 4; ++e) {
            int gi = i0 + ty * 4 + e;
            atomicAdd(&rowExp[gi], re[e]);
            atomicAdd(&rowPos[gi], rp[e]);
            atomicAdd(&rowCnt[gi], rc[e]);
        }
    }
}

// ---------------- finalize: per-row loss -> mean ----------------
__global__ void finalize_kernel(const float* __restrict__ rowExp,
                                const float* __restrict__ rowPos,
                                const float* __restrict__ rowCnt,
                                float* __restrict__ out) {
    float lsum = 0.0f;
    for (int i = threadIdx.x; i < N; i += 256) {
        float cnt  = rowCnt[i];
        float logd = logf(rowExp[i] + 1e-9f);
        lsum += (rowPos[i] - cnt * logd) / fmaxf(cnt, 1.0f);
    }
#pragma unroll
    for (int off = 32; off > 0; off >>= 1) lsum += __shfl_xor(lsum, off);
    __shared__ float wsum[4];
    if ((threadIdx.x & 63) == 0) wsum[threadIdx.x >> 6] = lsum;
    __syncthreads();
    if (threadIdx.x == 0)
        out[0] = -(wsum[0] + wsum[1] + wsum[2] + wsum[3]) / (float)N;
}

extern "C" void kernel_launch(void* const* d_in, const int* in_sizes, int n_in,
                              void* d_out, int out_size, void* d_ws, size_t ws_size,
                              hipStream_t stream) {
    const float* F      = (const float*)d_in[0];
    const int*   labels = (const int*)d_in[1];
    float* out = (float*)d_out;

    float* rnorm  = (float*)d_ws;       // N
    float* rowExp = rnorm + N;          // N
    float* rowPos = rowExp + N;         // N
    float* rowCnt = rowPos + N;         // N   (total 128 KB of ws)

    prep_kernel<<<N, 64, 0, stream>>>(F, rnorm, rowExp, rowPos, rowCnt);
    sim_kernel<<<dim3(N / BN, N / BM), 256, 0, stream>>>(F, labels, rnorm,
                                                         rowExp, rowPos, rowCnt);
    finalize_kernel<<<1, 256, 0, stream>>>(rowExp, rowPos, rowCnt, out);
}

// Round 2
// 178.678 us; speedup vs baseline: 2.4664x; 2.4664x over previous
//
#include <hip/hip_runtime.h>
#include <hip/hip_bf16.h>
#include <math.h>

// SupCon loss, N=8192 D=128 fp32 in, scalar fp32 out.
// Round 2: bf16 MFMA path. Fb = f_i * sqrt(10)/||f_i|| (temperature folded in),
// sim_ij = Fb_i . Fb_j computed with mfma_f32_16x16x32_bf16, fp32 accum.
// Per-row positive count comes from a label histogram (not accumulated in sim);
// positive-sum is pre-weighted by 1/max(cnt,1) and reduced to block scalars.

constexpr int N = 8192;
constexpr int D = 128;

typedef __attribute__((ext_vector_type(8))) short short8;  // 8 bf16 = 4 VGPRs
typedef __attribute__((ext_vector_type(4))) float f32x4;

__device__ __forceinline__ void gload_lds16(const void* g, void* s) {
    __builtin_amdgcn_global_load_lds(
        (const __attribute__((address_space(1))) unsigned int*)g,
        (__attribute__((address_space(3))) unsigned int*)s, 16, 0, 0);
}

// ---------------- zero: hist + posAcc (ws is 0xAA-poisoned every launch) ----
__global__ void zero_kernel(int* __restrict__ hist, float* __restrict__ posAcc) {
    int t = blockIdx.x * 256 + threadIdx.x;  // grid 4 x 256 = 1024
    hist[t] = 0;
    posAcc[t] = 0.0f;
}

// ---------------- prep: normalized+scaled bf16 rows, label histogram --------
__global__ void prep_kernel(const float* __restrict__ F,
                            const int* __restrict__ labels,
                            unsigned short* __restrict__ Fb,
                            float* __restrict__ rowExp,
                            int* __restrict__ hist) {
    int row = blockIdx.x;
    int l = threadIdx.x;  // 64 = 1 wave
    float2 v = ((const float2*)(F + (size_t)row * D))[l];
    float ss = v.x * v.x + v.y * v.y;
#pragma unroll
    for (int off = 32; off > 0; off >>= 1) ss += __shfl_xor(ss, off);
    float sc = sqrtf(10.0f / ss);  // sqrt(1/temp) folded into normalization
    __hip_bfloat16 hx = __float2bfloat16(v.x * sc);
    __hip_bfloat16 hy = __float2bfloat16(v.y * sc);
    ushort2 u;
    u.x = *(unsigned short*)&hx;
    u.y = *(unsigned short*)&hy;
    ((ushort2*)(Fb + (size_t)row * D))[l] = u;
    if (l == 0) {
        rowExp[row] = 0.0f;
        atomicAdd(&hist[labels[row]], 1);
    }
}

// ---------------- sim epilogue (templated on diagonal-block) ----------------
template <bool DIAG>
__device__ __forceinline__ void epilogue(
    const f32x4 (&acc)[4][4], int i0, int j0, int wy, int wx, int quad, int c,
    const int* __restrict__ labels, const int* __restrict__ hist,
    float* __restrict__ rowExp, float* __restrict__ posAcc, int slot) {
    int gj[4], lj[4];
#pragma unroll
    for (int n = 0; n < 4; ++n) {
        gj[n] = j0 + wx * 64 + n * 16 + c;
        lj[n] = labels[gj[n]];
    }
    float rp_acc = 0.0f;
#pragma unroll
    for (int m = 0; m < 4; ++m) {
        int gi[4], li[4];
#pragma unroll
        for (int r = 0; r < 4; ++r) {
            gi[r] = i0 + wy * 64 + m * 16 + quad * 4 + r;
            li[r] = labels[gi[r]];
        }
        float re[4] = {0, 0, 0, 0}, rp[4] = {0, 0, 0, 0};
#pragma unroll
        for (int n = 0; n < 4; ++n) {
#pragma unroll
            for (int r = 0; r < 4; ++r) {
                float s = acc[m][n][r];
                bool self = DIAG && (gi[r] == gj[n]);
                if (!self) {
                    re[r] += __expf(s);
                    if (li[r] == lj[n]) rp[r] += s;
                }
            }
        }
        // reduce over the 16 cols held by lanes quad*16 .. quad*16+15
#pragma unroll
        for (int off = 1; off < 16; off <<= 1) {
#pragma unroll
            for (int r = 0; r < 4; ++r) {
                re[r] += __shfl_xor(re[r], off);
                rp[r] += __shfl_xor(rp[r], off);
            }
        }
        if (c == 0) {
#pragma unroll
            for (int r = 0; r < 4; ++r) {
                atomicAdd(&rowExp[gi[r]], re[r]);
                int cnt = hist[li[r]] - 1;
                rp_acc += rp[r] / (float)max(cnt, 1);
            }
        }
    }
    if (c == 0) atomicAdd(&posAcc[slot], rp_acc);
}

// ---------------- sim: 128x128 tile, 4 waves, MFMA 16x16x32 bf16 ------------
__global__ __launch_bounds__(256, 2) void sim_kernel(
    const unsigned short* __restrict__ Fb, const int* __restrict__ labels,
    const int* __restrict__ hist, float* __restrict__ rowExp,
    float* __restrict__ posAcc) {
    __shared__ unsigned short At[128 * D];  // 32 KB
    __shared__ unsigned short Bt[128 * D];  // 32 KB

    const int i0 = blockIdx.y * 128, j0 = blockIdx.x * 128;
    const int t = threadIdx.x;
    const int w = t >> 6, l = t & 63;
    const int lr = l >> 4;   // row within 4-row group (16 lanes * 16B = 256B = 1 row)
    const int lq = l & 15;   // 16B-block slot within row

    // Stage both tiles via global_load_lds width=16. LDS dest is lane-
    // contiguous (wave-uniform base + lane*16, m104/m108); we XOR-swizzle the
    // *source* block index so compute-side ds_read_b128 is <=2-way conflicted.
#pragma unroll
    for (int it = 0; it < 8; ++it) {
        int rbase = w * 32 + it * 4;
        int r = rbase + lr;                 // tile row 0..127
        int q = lq ^ (r & 7);               // swizzled 8-elem block index
        gload_lds16(Fb + ((size_t)(i0 + r) * D + q * 8), &At[rbase * D]);
        gload_lds16(Fb + ((size_t)(j0 + r) * D + q * 8), &Bt[rbase * D]);
    }
    __syncthreads();

    const int c = l & 15, quad = l >> 4;
    const int wy = w >> 1, wx = w & 1;  // 64x64 quadrant per wave
    f32x4 acc[4][4] = {};

#pragma unroll
    for (int kk = 0; kk < 4; ++kk) {
        short8 af[4], bf[4];
        int sl = (kk * 4 + quad) ^ (c & 7);  // undo swizzle (row&7 == c&7)
#pragma unroll
        for (int m = 0; m < 4; ++m) {
            af[m] = *(const short8*)&At[(wy * 64 + m * 16 + c) * D + sl * 8];
            bf[m] = *(const short8*)&Bt[(wx * 64 + m * 16 + c) * D + sl * 8];
        }
#pragma unroll
        for (int m = 0; m < 4; ++m)
#pragma unroll
            for (int n = 0; n < 4; ++n)
                acc[m][n] = __builtin_amdgcn_mfma_f32_16x16x32_bf16(
                    af[m], bf[n], acc[m][n], 0, 0, 0);
    }

    int slot = ((blockIdx.y * 64 + blockIdx.x) * 4 + w) & 1023;
    if (i0 == j0)
        epilogue<true>(acc, i0, j0, wy, wx, quad, c, labels, hist, rowExp, posAcc, slot);
    else
        epilogue<false>(acc, i0, j0, wy, wx, quad, c, labels, hist, rowExp, posAcc, slot);
}

// ---------------- finalize ---------------------------------------------------
__global__ void finalize_kernel(const float* __restrict__ rowExp,
                                const int* __restrict__ labels,
                                const int* __restrict__ hist,
                                const float* __restrict__ posAcc,
                                float* __restrict__ out) {
    int t = threadIdx.x;
    float a = 0.0f;
    for (int i = t; i < N; i += 256) {
        if (hist[labels[i]] > 1) a += logf(rowExp[i] + 1e-9f);
    }
    for (int i = t; i < 1024; i += 256) a -= posAcc[i];
#pragma unroll
    for (int off = 32; off > 0; off >>= 1) a += __shfl_xor(a, off);
    __shared__ float ws4[4];
    if ((t & 63) == 0) ws4[t >> 6] = a;
    __syncthreads();
    if (t == 0) out[0] = (ws4[0] + ws4[1] + ws4[2] + ws4[3]) / (float)N;
}

extern "C" void kernel_launch(void* const* d_in, const int* in_sizes, int n_in,
                              void* d_out, int out_size, void* d_ws, size_t ws_size,
                              hipStream_t stream) {
    const float* F      = (const float*)d_in[0];
    const int*   labels = (const int*)d_in[1];
    float* out = (float*)d_out;

    unsigned short* Fb = (unsigned short*)d_ws;         // N*D bf16 = 2 MB
    float* rowExp = (float*)(Fb + (size_t)N * D);       // N floats
    int*   hist   = (int*)(rowExp + N);                 // 1024 ints
    float* posAcc = (float*)(hist + 1024);              // 1024 floats

    zero_kernel<<<4, 256, 0, stream>>>(hist, posAcc);
    prep_kernel<<<N, 64, 0, stream>>>(F, labels, Fb, rowExp, hist);
    sim_kernel<<<dim3(64, 64), 256, 0, stream>>>(Fb, labels, hist, rowExp, posAcc);
    finalize_kernel<<<1, 256, 0, stream>>>(rowExp, labels, hist, posAcc, out);
}

// Round 3
// 103.700 us; speedup vs baseline: 4.2497x; 1.7230x over previous
//
#include <hip/hip_runtime.h>
#include <hip/hip_bf16.h>
#include <math.h>

// SupCon loss, N=8192 D=128 fp32 in, scalar fp32 out.
// Round 3: symmetric triangular strips. Fb = f/||f|| * sqrt(10*log2e), so the
// MFMA accumulator is directly in log2 domain: exp(sim) = exp2(acc), and the
// positive-sum carries a single ln2 factor applied in finalize.
// Block = strip (ti, g): A-tile ti staged once, B-tiles tj in [max(ti,4g),4g+3].
// Row partials carried across the strip (4-level lane tree runs once/strip);
// column (transpose) contributions use the cheap 2-level quad shuffle per tile.

constexpr int N = 8192;
constexpr int D = 128;

typedef __attribute__((ext_vector_type(8))) short short8;  // 8 bf16 = 4 VGPRs
typedef __attribute__((ext_vector_type(4))) float f32x4;

__device__ __forceinline__ float fast_exp2(float x) {
#if __has_builtin(__builtin_amdgcn_exp2f)
    return __builtin_amdgcn_exp2f(x);
#else
    return __expf(x * 0.69314718056f);
#endif
}

__device__ __forceinline__ void gload_lds16(const void* g, void* s) {
    __builtin_amdgcn_global_load_lds(
        (const __attribute__((address_space(1))) unsigned int*)g,
        (__attribute__((address_space(3))) unsigned int*)s, 16, 0, 0);
}

// Stage one 128x128 bf16 tile (rows row0..row0+127) into LDS, source-side
// XOR swizzle so compute-side ds_read_b128 is conflict-free (dest must stay
// lane-contiguous per m104/m108).
__device__ __forceinline__ void stage_tile(const unsigned short* __restrict__ src,
                                           unsigned short* dst, int row0,
                                           int w, int lr, int lq) {
#pragma unroll
    for (int it = 0; it < 8; ++it) {
        int rbase = w * 32 + it * 4;
        int r = rbase + lr;
        int q = lq ^ (r & 7);
        gload_lds16(src + ((size_t)(row0 + r) * D + q * 8), dst + rbase * D);
    }
}

// ---------------- zero: label histogram (ws poisoned 0xAA every launch) -----
__global__ void zero_kernel(int* __restrict__ hist) {
    hist[threadIdx.x] = 0;  // <<<1,1024>>>
}

// ---------------- prep: bf16 rows scaled into log2 domain, histogram --------
__global__ void prep_kernel(const float* __restrict__ F,
                            const int* __restrict__ labels,
                            unsigned short* __restrict__ Fb,
                            float* __restrict__ rowExp,
                            float* __restrict__ rowPos,
                            int* __restrict__ hist) {
    int row = blockIdx.x * 4 + (threadIdx.x >> 6);
    int l = threadIdx.x & 63;
    float2 v = ((const float2*)(F + (size_t)row * D))[l];
    float ss = v.x * v.x + v.y * v.y;
#pragma unroll
    for (int off = 32; off > 0; off >>= 1) ss += __shfl_xor(ss, off);
    float sc = sqrtf(14.4269504089f / ss);  // 10 * log2(e), folded
    __hip_bfloat16 hx = __float2bfloat16(v.x * sc);
    __hip_bfloat16 hy = __float2bfloat16(v.y * sc);
    ushort2 u;
    u.x = *(unsigned short*)&hx;
    u.y = *(unsigned short*)&hy;
    ((ushort2*)(Fb + (size_t)row * D))[l] = u;
    if (l == 0) {
        rowExp[row] = 0.0f;
        rowPos[row] = 0.0f;
        atomicAdd(&hist[labels[row]], 1);
    }
}

// ---------------- sim: triangular strips, MFMA 16x16x32 bf16 ----------------
__global__ __launch_bounds__(256, 2) void sim_kernel(
    const unsigned short* __restrict__ Fb, const int* __restrict__ labels,
    float* __restrict__ rowExp, float* __restrict__ rowPos) {
    __shared__ unsigned short At[128 * D];  // 32 KB
    __shared__ unsigned short Bt[128 * D];  // 32 KB

    // decode strip: 544 blocks = sum over q of 4 rows * (16-q) groups
    int bid = blockIdx.x, q = 0, base = 0;
    while (bid >= base + 4 * (16 - q)) { base += 4 * (16 - q); ++q; }
    int rem = bid - base, ng = 16 - q;
    int ti = 4 * q + rem / ng;
    int g = 15 - (rem % ng);        // diag-crossing strip (g==q) scheduled last
    int tjs = max(ti, 4 * g), tje = 4 * g + 3;
    const int i0 = ti * 128;

    const int t = threadIdx.x, w = t >> 6, l = t & 63;
    const int lr = l >> 4, lq = l & 15;     // staging lane split
    const int c = l & 15, quad = l >> 4;    // MFMA lane split
    const int wy = w >> 1, wx = w & 1;      // 64x64 quadrant per wave

    stage_tile(Fb, At, i0, w, lr, lq);
    stage_tile(Fb, Bt, tjs * 128, w, lr, lq);

    // row labels for this wave's rows (strip-constant)
    int li[4][4];
#pragma unroll
    for (int m = 0; m < 4; ++m)
#pragma unroll
        for (int r = 0; r < 4; ++r)
            li[m][r] = labels[i0 + wy * 64 + m * 16 + quad * 4 + r];

    float RE[4][4] = {}, RP[4][4] = {};  // row partials, carried across strip

    for (int tj = tjs; tj <= tje; ++tj) {
        __syncthreads();  // staging of Bt (and At on first iter) complete
        int j0 = tj * 128;
        f32x4 acc[4][4] = {};
#pragma unroll
        for (int kk = 0; kk < 4; ++kk) {
            short8 af[4], bf[4];
            int sl = (kk * 4 + quad) ^ (c & 7);  // undo swizzle (row&7 == c&7)
#pragma unroll
            for (int m = 0; m < 4; ++m) {
                af[m] = *(const short8*)&At[(wy * 64 + m * 16 + c) * D + sl * 8];
                bf[m] = *(const short8*)&Bt[(wx * 64 + m * 16 + c) * D + sl * 8];
            }
#pragma unroll
            for (int m = 0; m < 4; ++m)
#pragma unroll
                for (int n = 0; n < 4; ++n)
                    acc[m][n] = __builtin_amdgcn_mfma_f32_16x16x32_bf16(
                        af[m], bf[n], acc[m][n], 0, 0, 0);
        }
        __syncthreads();  // all waves done reading Bt
        if (tj < tje) stage_tile(Fb, Bt, (tj + 1) * 128, w, lr, lq);  // overlap DMA

        // ---- epilogue (registers only; overlaps the B DMA) ----
        int lj[4];
#pragma unroll
        for (int n = 0; n < 4; ++n) lj[n] = labels[j0 + wx * 64 + n * 16 + c];
        const bool diag = (tj == ti);
        float ce[4] = {}, cp[4] = {};
#pragma unroll
        for (int m = 0; m < 4; ++m) {
#pragma unroll
            for (int n = 0; n < 4; ++n) {
#pragma unroll
                for (int r = 0; r < 4; ++r) {
                    float s2 = acc[m][n][r];
                    bool self = diag && ((wy * 64 + m * 16 + quad * 4 + r) ==
                                         (wx * 64 + n * 16 + c));
                    float e = self ? 0.0f : fast_exp2(s2);
                    float p = (!self && li[m][r] == lj[n]) ? s2 : 0.0f;
                    RE[m][r] += e;
                    RP[m][r] += p;
                    ce[n] += e;
                    cp[n] += p;
                }
            }
        }
        if (!diag) {
            // transpose contribution: reduce down rows (quads) — 2 levels only
#pragma unroll
            for (int n = 0; n < 4; ++n) {
                ce[n] += __shfl_xor(ce[n], 16);
                ce[n] += __shfl_xor(ce[n], 32);
                cp[n] += __shfl_xor(cp[n], 16);
                cp[n] += __shfl_xor(cp[n], 32);
            }
            if (quad == 0) {
#pragma unroll
                for (int n = 0; n < 4; ++n) {
                    int gj = j0 + wx * 64 + n * 16 + c;
                    atomicAdd(&rowExp[gj], ce[n]);
                    atomicAdd(&rowPos[gj], cp[n]);
                }
            }
        }
    }

    // strip end: row reduction across the 16 col-lanes (once per strip)
#pragma unroll
    for (int m = 0; m < 4; ++m)
#pragma unroll
        for (int r = 0; r < 4; ++r) {
#pragma unroll
            for (int off = 1; off < 16; off <<= 1) {
                RE[m][r] += __shfl_xor(RE[m][r], off);
                RP[m][r] += __shfl_xor(RP[m][r], off);
            }
        }
    if (c == 0) {
#pragma unroll
        for (int m = 0; m < 4; ++m)
#pragma unroll
            for (int r = 0; r < 4; ++r) {
                int gi = i0 + wy * 64 + m * 16 + quad * 4 + r;
                atomicAdd(&rowExp[gi], RE[m][r]);
                atomicAdd(&rowPos[gi], RP[m][r]);
            }
    }
}

// ---------------- finalize: loss = mean_i [ln(denom_i) - ln2*rowPos_i/cnt_i]
__global__ void finalize_kernel(const float* __restrict__ rowExp,
                                const float* __restrict__ rowPos,
                                const int* __restrict__ labels,
                                const int* __restrict__ hist,
                                float* __restrict__ out) {
    int t = threadIdx.x;  // 1024 threads -> 8-deep load pipeline
    float a = 0.0f;
    for (int i = t; i < N; i += 1024) {
        int cnt = hist[labels[i]] - 1;
        if (cnt > 0)
            a += logf(rowExp[i] + 1e-9f) -
                 0.69314718056f * rowPos[i] / (float)cnt;
    }
#pragma unroll
    for (int off = 32; off > 0; off >>= 1) a += __shfl_xor(a, off);
    __shared__ float ws16[16];
    if ((t & 63) == 0) ws16[t >> 6] = a;
    __syncthreads();
    if (t == 0) {
        float s = 0.0f;
#pragma unroll
        for (int i = 0; i < 16; ++i) s += ws16[i];
        out[0] = s / (float)N;
    }
}

extern "C" void kernel_launch(void* const* d_in, const int* in_sizes, int n_in,
                              void* d_out, int out_size, void* d_ws, size_t ws_size,
                              hipStream_t stream) {
    const float* F      = (const float*)d_in[0];
    const int*   labels = (const int*)d_in[1];
    float* out = (float*)d_out;

    unsigned short* Fb = (unsigned short*)d_ws;     // N*D bf16 = 2 MB
    float* rowExp = (float*)(Fb + (size_t)N * D);   // N floats
    float* rowPos = rowExp + N;                     // N floats
    int*   hist   = (int*)(rowPos + N);             // 1024 ints

    zero_kernel<<<1, 1024, 0, stream>>>(hist);
    prep_kernel<<<N / 4, 256, 0, stream>>>(F, labels, Fb, rowExp, rowPos, hist);
    sim_kernel<<<544, 256, 0, stream>>>(Fb, labels, rowExp, rowPos);
    finalize_kernel<<<1, 1024, 0, stream>>>(rowExp, rowPos, labels, hist, out);
}